// Round 10
// baseline (304.631 us; speedup 1.0000x reference)
//
#include <hip/hip_runtime.h>
#include <hip/hip_bf16.h>

#define NN 50000
#define EE 800000
#define EN (EE + NN)      // edges including self-loops
#define IN_DIM 128
#define HID 32
#define HEADS 4
#define F1 (HEADS * HID)  // 128
#define NEG 0.2f

typedef __hip_bfloat16 bf16;
typedef __bf16 bf16x8 __attribute__((ext_vector_type(8)));
typedef float f32x4 __attribute__((ext_vector_type(4)));

__device__ __forceinline__ float cvt(float v) { return v; }
__device__ __forceinline__ float cvt(bf16 v)  { return __bfloat162float(v); }

__device__ __forceinline__ float bflo(unsigned u) {
    union { unsigned u; float f; } v; v.u = u << 16; return v.f;
}
__device__ __forceinline__ float bfhi(unsigned u) {
    union { unsigned u; float f; } v; v.u = u & 0xFFFF0000u; return v.f;
}

__device__ __forceinline__ unsigned short f2bf_bits(float f) {
    union { float f; unsigned u; } v; v.f = f;
    unsigned r = v.u + 0x7FFFu + ((v.u >> 16) & 1u);
    return (unsigned short)(r >> 16);
}

__device__ __forceinline__ unsigned short f2h_bits(float f) {
    _Float16 h = (_Float16)f;
    union { _Float16 h; unsigned short s; } v; v.h = h; return v.s;
}
__device__ __forceinline__ float h2f(unsigned short s) {
    union { _Float16 h; unsigned short s; } v; v.s = s; return (float)v.h;
}

// exp for head h out of a packed record (y = heads 0,1 ; z = heads 2,3)
__device__ __forceinline__ float rec_exp(uint4 r, int h) {
    unsigned w = (h & 2) ? r.z : r.y;
    unsigned short b = (h & 1) ? (unsigned short)(w >> 16) : (unsigned short)(w & 0xFFFFu);
    return h2f(b);
}

// ---- prep (fused detector): flags + W1T[n][k], W2T[n][k] bf16 ----------------
__global__ void k_prep(const void* xv, const void* eiv, const void* W1v, const void* W2v,
                       int* __restrict__ flags,
                       unsigned short* __restrict__ W1T, unsigned short* __restrict__ W2T) {
    __shared__ int sf;
    const int t = threadIdx.x;
    if (t < 64) {
        const unsigned* xw = (const unsigned*)xv;
        const unsigned* ew = (const unsigned*)eiv;
        int lo_nz = 0, huge = 0, hi_nz = 0;
        for (int j = 0; j < 4; ++j) {
            unsigned w = xw[t * 4 + j];
            unsigned lo = w & 0xFFFFu;
            if (lo != 0u) lo_nz = 1;
            if (((lo >> 7) & 0xFFu) >= 0xC0u) huge = 1;
            unsigned eo = ew[(t * 4 + j) * 2 + 1];
            if (eo != 0u) hi_nz = 1;
        }
        unsigned long long m_lo = __ballot(lo_nz);
        unsigned long long m_hg = __ballot(huge);
        unsigned long long m_hi = __ballot(hi_nz);
        if (t == 0) {
            int f0 = (m_lo == 0ull || m_hg != 0ull) ? 1 : 0;
            int f1 = (m_hi == 0ull) ? 1 : 0;
            flags[0] = f0; flags[1] = f1;
            sf = f0;
        }
    }
    __syncthreads();
    const int f32in = sf;
    const unsigned short* w1g = (const unsigned short*)W1v;
    const float* w1f = (const float*)W1v;
    for (int i = 0; i < 64; ++i) {
        int id = i * 256 + t;                 // n*128+k
        int n = id >> 7, k = id & 127;
        W1T[id] = f32in ? f2bf_bits(w1f[k * 128 + n]) : w1g[k * 128 + n];
    }
    const unsigned short* w2g = (const unsigned short*)W2v;
    const float* w2f = (const float*)W2v;
    for (int i = 0; i < 16; ++i) {
        int id = i * 256 + t;                 // n*128+k  (n<32)
        int n = id >> 7, k = id & 127;
        W2T[id] = f32in ? f2bf_bits(w2f[k * 32 + n]) : w2g[k * 32 + n];
    }
}

// ---------------- edge decode helpers ----------------------------------------
template <typename IT>
__device__ __forceinline__ void get_sd(const IT* __restrict__ ei, int idx, int& s, int& d) {
    if (idx < EE) { s = (int)ei[idx]; d = (int)ei[EE + idx]; }
    else          { s = d = idx - EE; }
}
template <typename IT>
__device__ __forceinline__ int dst_of(const IT* __restrict__ ei, int idx) {
    return idx < EE ? (int)ei[EE + idx] : idx - EE;
}

// ---------------- Layer 1 linear via MFMA: h1(bf16) = x @ W1, + logits --------
#define MROWS 64
#define LDK 136   // padded LDS row stride (elements) -> 272 B, 16B-aligned frags

__global__ __launch_bounds__(256) void k_lin1_mfma(
    const void* xv, const unsigned short* __restrict__ W1T,
    const void* as1v, const void* ad1v,
    const int* __restrict__ flags, unsigned* __restrict__ h1,
    float* __restrict__ als, float* __restrict__ ald)
{
    __shared__ __align__(16) char smem[(MROWS + 128) * LDK * 2];  // 52,224 B
    unsigned short* xs  = (unsigned short*)smem;       // [MROWS][LDK] bf16 bits
    unsigned short* w1t = xs + MROWS * LDK;            // [128][LDK]   (n-major)
    float* hs = (float*)smem;                          // phase2 alias: [MROWS][132]
    __shared__ float sa[F1], sd[F1];

    const int t = threadIdx.x;
    const int row0 = blockIdx.x * MROWS;
    const int f32in = flags[0];

    if (t < F1) {
        sa[t] = f32in ? ((const float*)as1v)[t] : cvt(((const bf16*)as1v)[t]);
        sd[t] = f32in ? ((const float*)ad1v)[t] : cvt(((const bf16*)ad1v)[t]);
    }
    if (!f32in) {
        const uint4* xg = (const uint4*)xv;            // 16 B = 8 bf16
        for (int i = 0; i < 4; ++i) {
            int id = i * 256 + t;                      // 0..1023
            int m = id >> 4, seg = id & 15;
            int gr = row0 + m;
            uint4 val = (gr < NN) ? xg[(size_t)gr * 16 + seg] : make_uint4(0, 0, 0, 0);
            *(uint4*)&xs[m * LDK + seg * 8] = val;
        }
    } else {
        const float* xf = (const float*)xv;
        for (int i = 0; i < 32; ++i) {
            int id = i * 256 + t;
            int m = id >> 7, c = id & 127;
            int gr = row0 + m;
            xs[m * LDK + c] = (gr < NN) ? f2bf_bits(xf[(size_t)gr * 128 + c]) : 0;
        }
    }
    {
        const uint4* wg = (const uint4*)W1T;           // [128][16] uint4, n-major
        for (int i = 0; i < 8; ++i) {
            int id = i * 256 + t;                      // 0..2047 = n*16+seg
            int n = id >> 4, seg = id & 15;
            *(uint4*)&w1t[n * LDK + seg * 8] = wg[id];
        }
    }
    __syncthreads();

    const int wave = t >> 6, lane = t & 63, quad = lane >> 4, l16 = lane & 15;
    f32x4 acc[8];
#pragma unroll
    for (int ni = 0; ni < 8; ++ni) acc[ni] = (f32x4){0.f, 0.f, 0.f, 0.f};

    const int arow = wave * 16 + l16;
#pragma unroll
    for (int kc = 0; kc < 4; ++kc) {
        int ko = kc * 32 + quad * 8;
        bf16x8 av = *(const bf16x8*)&xs[arow * LDK + ko];
#pragma unroll
        for (int ni = 0; ni < 8; ++ni) {
            bf16x8 bv = *(const bf16x8*)&w1t[(ni * 16 + l16) * LDK + ko];
            acc[ni] = __builtin_amdgcn_mfma_f32_16x16x32_bf16(av, bv, acc[ni], 0, 0, 0);
        }
    }
    __syncthreads();   // staging LDS dead; reuse as hs

#pragma unroll
    for (int ni = 0; ni < 8; ++ni)
#pragma unroll
        for (int r = 0; r < 4; ++r) {
            int m = wave * 16 + quad * 4 + r;          // C/D: row=quad*4+reg, col=l16
            hs[m * 132 + ni * 16 + l16] = acc[ni][r];
        }
    __syncthreads();

    for (int i = 0; i < 16; ++i) {
        int id = i * 256 + t;                          // 0..4095 word index
        int m = id >> 6, wd = id & 63;
        int gr = row0 + m;
        if (gr < NN) {
            unsigned pw = (unsigned)f2bf_bits(hs[m * 132 + 2 * wd]) |
                          ((unsigned)f2bf_bits(hs[m * 132 + 2 * wd + 1]) << 16);
            h1[(size_t)gr * 64 + wd] = pw;
        }
    }
    {
        int m = t >> 2, h = t & 3;                     // 64 nodes x 4 heads
        int gr = row0 + m;
        if (gr < NN) {
            float ps = 0.f, pd = 0.f;
#pragma unroll
            for (int j = 0; j < 32; ++j) {
                float v = hs[m * 132 + h * 32 + j];
                ps += v * sa[h * 32 + j];
                pd += v * sd[h * 32 + j];
            }
            als[gr * 4 + h] = ps;
            ald[gr * 4 + h] = pd;
        }
    }
}

// ---------------- CSR build: histogram(+rank) + 2-kernel scan -----------------
#define SCAN_B 196   // ceil(NN/256)

__global__ void k_hist(const void* ei, const int* __restrict__ flags,
                       int* __restrict__ counts, int* __restrict__ rank) {
    int idx = blockIdx.x * blockDim.x + threadIdx.x;
    if (idx >= EN) return;
    int d = flags[1] ? dst_of<long long>((const long long*)ei, idx)
                     : dst_of<int>((const int*)ei, idx);
    rank[idx] = atomicAdd(&counts[d], 1);
}

__global__ void k_scanA(const int* __restrict__ counts, int* __restrict__ bsum) {
    __shared__ int sh[256];
    int i = blockIdx.x * 256 + threadIdx.x;
    sh[threadIdx.x] = (i < NN) ? counts[i] : 0;
    __syncthreads();
    for (int off = 128; off > 0; off >>= 1) {
        if (threadIdx.x < off) sh[threadIdx.x] += sh[threadIdx.x + off];
        __syncthreads();
    }
    if (threadIdx.x == 0) bsum[blockIdx.x] = sh[0];
}

// per-block: tree-reduce bsum[0..b) for the base, then local scan
__global__ void k_scanC(const int* __restrict__ counts, const int* __restrict__ bsum,
                        int* __restrict__ offsets) {
    __shared__ int red[256];
    __shared__ int sh[256];
    const int t = threadIdx.x, b = blockIdx.x;
    red[t] = (t < b) ? bsum[t] : 0;        // b <= 195 < 256, so bsum[t] valid when t<b
    __syncthreads();
    for (int off = 128; off > 0; off >>= 1) {
        if (t < off) red[t] += red[t + off];
        __syncthreads();
    }
    const int base = red[0];
    int i = b * 256 + t;
    int v = (i < NN) ? counts[i] : 0;
    sh[t] = v;
    __syncthreads();
    for (int off = 1; off < 256; off <<= 1) {
        int u = (t >= off) ? sh[t - off] : 0;
        __syncthreads();
        sh[t] += u;
        __syncthreads();
    }
    if (i < NN) {
        offsets[i] = base + sh[t] - v;
    } else if (i == NN) {
        offsets[NN] = EN;                    // total is static
    }
}

// ---- scatter (no atomic): one 16B record/edge = {src, exp01, exp23, 0} -------
__global__ void k_scatter(const void* ei, const int* __restrict__ flags,
                          const int* __restrict__ offsets, const int* __restrict__ rank,
                          const float4* __restrict__ als, const float4* __restrict__ ald,
                          uint4* __restrict__ rec) {
    int idx = blockIdx.x * blockDim.x + threadIdx.x;
    if (idx >= EN) return;
    int s, d;
    if (flags[1]) get_sd<long long>((const long long*)ei, idx, s, d);
    else          get_sd<int>((const int*)ei, idx, s, d);
    int slot = offsets[d] + rank[idx];
    float4 a = als[s], b = ald[d];
    float e0 = a.x + b.x, e1 = a.y + b.y, e2 = a.z + b.z, e3 = a.w + b.w;
    e0 = e0 > 0.f ? e0 : NEG * e0;
    e1 = e1 > 0.f ? e1 : NEG * e1;
    e2 = e2 > 0.f ? e2 : NEG * e2;
    e3 = e3 > 0.f ? e3 : NEG * e3;
    unsigned w0 = (unsigned)f2h_bits(__expf(e0)) | ((unsigned)f2h_bits(__expf(e1)) << 16);
    unsigned w1 = (unsigned)f2h_bits(__expf(e2)) | ((unsigned)f2h_bits(__expf(e3)) << 16);
    rec[slot] = make_uint4((unsigned)s, w0, w1, 0u);
}

// ---- Layer 1 aggregate FUSED with mid-MLP:
//      edge loop (half-wave/edge, x4 unroll) -> softmax -> b1+ELU (regs)
//      -> in-wave 128->32 GEMV vs W2 (VGPR rows + LDS hm broadcast)
//      -> h2(f16) + layer-2 logits. No hm global round-trip, no k_mid. --------
__global__ __launch_bounds__(256) void k_agg1(
    const int* __restrict__ offsets, const uint4* __restrict__ rec,
    const bf16* __restrict__ h1, const void* b1v,
    const unsigned short* __restrict__ W2T,
    const void* as2v, const void* ad2v, const int* __restrict__ flags,
    unsigned short* __restrict__ h2, float* __restrict__ als2, float* __restrict__ ald2)
{
    __shared__ unsigned hmbuf[4][64];      // per-wave bf16-packed hm row
    const int lane = threadIdx.x & 63;
    const int w = threadIdx.x >> 6;
    const int d = blockIdx.x * 4 + w;
    const int q = lane >> 5;           // half: even/odd edges, later k-half
    const int u = lane & 31;           // uint2 index in row -> channels 4u..4u+3
    const int h = u >> 3;              // head of these channels
    const int start = offsets[d], end = offsets[d + 1];
    const uint2* rows = (const uint2*)h1;   // 32 uint2 per 256 B row

    float A0[4] = {0,0,0,0}, A1[4] = {0,0,0,0}, A2[4] = {0,0,0,0}, A3[4] = {0,0,0,0};
    float D[4] = {0,0,0,0};
    int e = start + q;
    for (; e + 6 < end; e += 8) {
        uint4 r0 = rec[e],     r1 = rec[e + 2];
        uint4 r2 = rec[e + 4], r3 = rec[e + 6];
        float x0 = rec_exp(r0, h), x1 = rec_exp(r1, h);
        float x2 = rec_exp(r2, h), x3 = rec_exp(r3, h);
        uint2 u0 = rows[r0.x * 32 + u], u1 = rows[r1.x * 32 + u];
        uint2 u2 = rows[r2.x * 32 + u], u3 = rows[r3.x * 32 + u];
        A0[0] += x0 * bflo(u0.x); A0[1] += x0 * bfhi(u0.x);
        A0[2] += x0 * bflo(u0.y); A0[3] += x0 * bfhi(u0.y); D[0] += x0;
        A1[0] += x1 * bflo(u1.x); A1[1] += x1 * bfhi(u1.x);
        A1[2] += x1 * bflo(u1.y); A1[3] += x1 * bfhi(u1.y); D[1] += x1;
        A2[0] += x2 * bflo(u2.x); A2[1] += x2 * bfhi(u2.x);
        A2[2] += x2 * bflo(u2.y); A2[3] += x2 * bfhi(u2.y); D[2] += x2;
        A3[0] += x3 * bflo(u3.x); A3[1] += x3 * bfhi(u3.x);
        A3[2] += x3 * bflo(u3.y); A3[3] += x3 * bfhi(u3.y); D[3] += x3;
    }
    for (; e < end; e += 2) {
        uint4 r0 = rec[e];
        float x0 = rec_exp(r0, h);
        uint2 u0 = rows[r0.x * 32 + u];
        A0[0] += x0 * bflo(u0.x); A0[1] += x0 * bfhi(u0.x);
        A0[2] += x0 * bflo(u0.y); A0[3] += x0 * bfhi(u0.y); D[0] += x0;
    }
    float a0 = A0[0] + A1[0] + A2[0] + A3[0];
    float a1 = A0[1] + A1[1] + A2[1] + A3[1];
    float a2 = A0[2] + A1[2] + A2[2] + A3[2];
    float a3 = A0[3] + A1[3] + A2[3] + A3[3];
    float dsum = D[0] + D[1] + D[2] + D[3];
    a0 += __shfl_xor(a0, 32); a1 += __shfl_xor(a1, 32);
    a2 += __shfl_xor(a2, 32); a3 += __shfl_xor(a3, 32);
    dsum += __shfl_xor(dsum, 32);

    // ---- bias + ELU (all lanes; both halves hold identical sums) ----
    const int f32in = flags[0];
    float inv = 1.f / (dsum + 1e-16f);
    float bb0, bb1, bb2, bb3;
    if (f32in) {
        float4 bb = ((const float4*)b1v)[u];
        bb0 = bb.x; bb1 = bb.y; bb2 = bb.z; bb3 = bb.w;
    } else {
        uint2 ub = ((const uint2*)b1v)[u];
        bb0 = bflo(ub.x); bb1 = bfhi(ub.x); bb2 = bflo(ub.y); bb3 = bfhi(ub.y);
    }
    float v0 = a0 * inv + bb0, v1 = a1 * inv + bb1;
    float v2 = a2 * inv + bb2, v3 = a3 * inv + bb3;
    v0 = v0 > 0.f ? v0 : (__expf(v0) - 1.f);   // ELU
    v1 = v1 > 0.f ? v1 : (__expf(v1) - 1.f);
    v2 = v2 > 0.f ? v2 : (__expf(v2) - 1.f);
    v3 = v3 > 0.f ? v3 : (__expf(v3) - 1.f);
    unsigned hw0 = (unsigned)f2bf_bits(v0) | ((unsigned)f2bf_bits(v1) << 16);
    unsigned hw1 = (unsigned)f2bf_bits(v2) | ((unsigned)f2bf_bits(v3) << 16);
    if (q == 0) {
        hmbuf[w][2 * u]     = hw0;
        hmbuf[w][2 * u + 1] = hw1;
    }

    // ---- W2 row-half into VGPRs: lane = output channel j=u, k-half q ----
    const uint4* w2g = (const uint4*)W2T;    // [32][16] uint4, row-major
    uint4 w2r[8];
#pragma unroll
    for (int g = 0; g < 8; ++g) w2r[g] = w2g[u * 16 + q * 8 + g];

    __syncthreads();   // hm row visible (all waves reach: loops are finite)

    // ---- GEMV: h2[j] = sum_k hm[k] * W2T[j][k], split k across halves ----
    float h2j = 0.f;
#pragma unroll
    for (int g = 0; g < 8; ++g) {
        uint4 wv = w2r[g];
        uint4 hv = *(const uint4*)&hmbuf[w][q * 32 + g * 4];
        h2j += bflo(hv.x) * bflo(wv.x) + bfhi(hv.x) * bfhi(wv.x)
             + bflo(hv.y) * bflo(wv.y) + bfhi(hv.y) * bfhi(wv.y)
             + bflo(hv.z) * bflo(wv.z) + bfhi(hv.z) * bfhi(wv.z)
             + bflo(hv.w) * bflo(wv.w) + bfhi(hv.w) * bfhi(wv.w);
    }
    h2j += __shfl_xor(h2j, 32);
    if (q == 0) h2[(size_t)d * 32 + u] = f2h_bits(h2j);

    // ---- layer-2 logits: butterfly over the 32 output channels ----
    float saj = f32in ? ((const float*)as2v)[u] : cvt(((const bf16*)as2v)[u]);
    float sdj = f32in ? ((const float*)ad2v)[u] : cvt(((const bf16*)ad2v)[u]);
    float ps = h2j * saj, pd = h2j * sdj;
#pragma unroll
    for (int mask = 1; mask < 32; mask <<= 1) {
        ps += __shfl_xor(ps, mask);
        pd += __shfl_xor(pd, mask);
    }
    if (lane == 0) { als2[d] = ps; ald2[d] = pd; }
}

// ---- Layer 2 aggregate: 1 wave/node, 16 lanes/edge (q=0..3), unroll x2 -------
__global__ __launch_bounds__(256) void k_agg2(
    const int* __restrict__ offsets, const uint4* __restrict__ rec,
    const float* __restrict__ als2, const float* __restrict__ ald2,
    const unsigned* __restrict__ h2,   // f16 pairs, 16 per row
    const void* b2v, const int* __restrict__ flags, void* out)
{
    const int lane = threadIdx.x & 63;
    const int node = blockIdx.x * 4 + (threadIdx.x >> 6);
    const int q = lane >> 4;           // 0..3: edge sub-stream
    const int u = lane & 15;           // uint index: channels 2u, 2u+1
    const int start = offsets[node], end = offsets[node + 1];
    const float adv = ald2[node];

    float A0 = 0.f, A1 = 0.f, B0 = 0.f, B1 = 0.f, D0 = 0.f, D1 = 0.f;
    int e = start + q;
    for (; e + 4 < end; e += 8) {
        int s0 = (int)rec[e].x, s1 = (int)rec[e + 4].x;
        float e0 = als2[s0] + adv, e1 = als2[s1] + adv;
        e0 = e0 > 0.f ? e0 : NEG * e0;
        e1 = e1 > 0.f ? e1 : NEG * e1;
        float x0 = __expf(e0), x1 = __expf(e1);
        unsigned w0 = h2[s0 * 16 + u];
        unsigned w1 = h2[s1 * 16 + u];
        A0 += x0 * h2f((unsigned short)(w0 & 0xFFFFu));
        A1 += x0 * h2f((unsigned short)(w0 >> 16));  D0 += x0;
        B0 += x1 * h2f((unsigned short)(w1 & 0xFFFFu));
        B1 += x1 * h2f((unsigned short)(w1 >> 16));  D1 += x1;
    }
    for (; e < end; e += 4) {
        int s0 = (int)rec[e].x;
        float e0 = als2[s0] + adv;
        e0 = e0 > 0.f ? e0 : NEG * e0;
        float x0 = __expf(e0);
        unsigned w0 = h2[s0 * 16 + u];
        A0 += x0 * h2f((unsigned short)(w0 & 0xFFFFu));
        A1 += x0 * h2f((unsigned short)(w0 >> 16));  D0 += x0;
    }
    float a0 = A0 + B0, a1 = A1 + B1, dsum = D0 + D1;
    a0 += __shfl_xor(a0, 16); a1 += __shfl_xor(a1, 16); dsum += __shfl_xor(dsum, 16);
    a0 += __shfl_xor(a0, 32); a1 += __shfl_xor(a1, 32); dsum += __shfl_xor(dsum, 32);
    if (q == 0) {
        float inv = 1.f / (dsum + 1e-16f);
        float r0 = a0 * inv, r1 = a1 * inv;
        if (flags[0]) {
            float2 bb = ((const float2*)b2v)[u];
            ((float2*)out)[(size_t)node * 16 + u] = make_float2(r0 + bb.x, r1 + bb.y);
        } else {
            unsigned ub = ((const unsigned*)b2v)[u];
            r0 += bflo(ub); r1 += bfhi(ub);
            ((unsigned*)out)[(size_t)node * 16 + u] =
                (unsigned)f2bf_bits(r0) | ((unsigned)f2bf_bits(r1) << 16);
        }
    }
}

extern "C" void kernel_launch(void* const* d_in, const int* in_sizes, int n_in,
                              void* d_out, int out_size, void* d_ws, size_t ws_size,
                              hipStream_t stream) {
    const void* x    = d_in[0];
    const void* ei   = d_in[1];
    const void* W1   = d_in[2];
    const void* a_s1 = d_in[3];
    const void* a_d1 = d_in[4];
    const void* b1   = d_in[5];
    const void* W2   = d_in[6];
    const void* a_s2 = d_in[7];
    const void* a_d2 = d_in[8];
    const void* b2v  = d_in[9];

    // ---- workspace layout (~35.3 MB) ----
    int*   flags  = (int*)d_ws;
    char*  pc     = (char*)d_ws + 256;
    bf16*  h1     = (bf16*)pc;             pc += (size_t)NN * F1 * 2;   // 12.8 MB
    uint4* rec    = (uint4*)pc;            pc += (size_t)EN * 16;      // 13.6 MB
    int*   rank   = (int*)pc;              pc += (size_t)EN * 4;       // 3.4 MB
    unsigned short* h2 = (unsigned short*)pc; pc += (size_t)NN * HID * 2;  // 3.2 MB
    float* al_s1  = (float*)pc;            pc += (size_t)NN * HEADS * 4;
    float* al_d1  = (float*)pc;            pc += (size_t)NN * HEADS * 4;
    float* al_s2  = (float*)pc;            pc += (size_t)NN * 4;
    float* al_d2  = (float*)pc;            pc += (size_t)NN * 4;
    int*   offs   = (int*)pc;              pc += (size_t)(NN + 4) * 4;
    int*   counts = (int*)pc;              pc += (size_t)NN * 4;
    unsigned short* W1T = (unsigned short*)pc; pc += (size_t)128 * 128 * 2;
    unsigned short* W2T = (unsigned short*)pc; pc += (size_t)32 * 128 * 2;
    int*   bsum   = (int*)pc;              pc += SCAN_B * 4;

    hipMemsetAsync(counts, 0, (size_t)NN * sizeof(int), stream);

    k_prep<<<1, 256, 0, stream>>>(x, ei, W1, W2, flags, W1T, W2T);
    k_hist<<<(EN + 255) / 256, 256, 0, stream>>>(ei, flags, counts, rank);
    k_scanA<<<SCAN_B, 256, 0, stream>>>(counts, bsum);
    k_scanC<<<SCAN_B, 256, 0, stream>>>(counts, bsum, offs);
    k_lin1_mfma<<<(NN + MROWS - 1) / MROWS, 256, 0, stream>>>(x, W1T, a_s1, a_d1,
                                                              flags, (unsigned*)h1,
                                                              al_s1, al_d1);
    k_scatter<<<(EN + 255) / 256, 256, 0, stream>>>(ei, flags, offs, rank,
                                                    (const float4*)al_s1,
                                                    (const float4*)al_d1, rec);
    k_agg1<<<NN / 4, 256, 0, stream>>>(offs, rec, h1, b1, W2T, a_s2, a_d2, flags,
                                       h2, al_s2, al_d2);
    k_agg2<<<NN / 4, 256, 0, stream>>>(offs, rec, al_s2, al_d2, (const unsigned*)h2,
                                       b2v, flags, d_out);
}

// Round 11
// 261.598 us; speedup vs baseline: 1.1645x; 1.1645x over previous
//
#include <hip/hip_runtime.h>
#include <hip/hip_bf16.h>

#define NN 50000
#define EE 800000
#define EN (EE + NN)      // edges including self-loops
#define IN_DIM 128
#define HID 32
#define HEADS 4
#define F1 (HEADS * HID)  // 128
#define NEG 0.2f

typedef __hip_bfloat16 bf16;
typedef __bf16 bf16x8 __attribute__((ext_vector_type(8)));
typedef float f32x4 __attribute__((ext_vector_type(4)));

__device__ __forceinline__ float cvt(float v) { return v; }
__device__ __forceinline__ float cvt(bf16 v)  { return __bfloat162float(v); }

__device__ __forceinline__ float bflo(unsigned u) {
    union { unsigned u; float f; } v; v.u = u << 16; return v.f;
}
__device__ __forceinline__ float bfhi(unsigned u) {
    union { unsigned u; float f; } v; v.u = u & 0xFFFF0000u; return v.f;
}

__device__ __forceinline__ unsigned short f2bf_bits(float f) {
    union { float f; unsigned u; } v; v.f = f;
    unsigned r = v.u + 0x7FFFu + ((v.u >> 16) & 1u);
    return (unsigned short)(r >> 16);
}

__device__ __forceinline__ unsigned short f2h_bits(float f) {
    _Float16 h = (_Float16)f;
    union { _Float16 h; unsigned short s; } v; v.h = h; return v.s;
}
__device__ __forceinline__ float h2f(unsigned short s) {
    union { _Float16 h; unsigned short s; } v; v.s = s; return (float)v.h;
}

// exp for head h out of a packed record (y = heads 0,1 ; z = heads 2,3)
__device__ __forceinline__ float rec_exp(uint4 r, int h) {
    unsigned w = (h & 2) ? r.z : r.y;
    unsigned short b = (h & 1) ? (unsigned short)(w >> 16) : (unsigned short)(w & 0xFFFFu);
    return h2f(b);
}

// ---- prep (fused detector): flags + W1T[n][k], W2T[n][k] bf16 ----------------
__global__ void k_prep(const void* xv, const void* eiv, const void* W1v, const void* W2v,
                       int* __restrict__ flags,
                       unsigned short* __restrict__ W1T, unsigned short* __restrict__ W2T) {
    __shared__ int sf;
    const int t = threadIdx.x;
    if (t < 64) {
        const unsigned* xw = (const unsigned*)xv;
        const unsigned* ew = (const unsigned*)eiv;
        int lo_nz = 0, huge = 0, hi_nz = 0;
        for (int j = 0; j < 4; ++j) {
            unsigned w = xw[t * 4 + j];
            unsigned lo = w & 0xFFFFu;
            if (lo != 0u) lo_nz = 1;
            if (((lo >> 7) & 0xFFu) >= 0xC0u) huge = 1;
            unsigned eo = ew[(t * 4 + j) * 2 + 1];
            if (eo != 0u) hi_nz = 1;
        }
        unsigned long long m_lo = __ballot(lo_nz);
        unsigned long long m_hg = __ballot(huge);
        unsigned long long m_hi = __ballot(hi_nz);
        if (t == 0) {
            int f0 = (m_lo == 0ull || m_hg != 0ull) ? 1 : 0;
            int f1 = (m_hi == 0ull) ? 1 : 0;
            flags[0] = f0; flags[1] = f1;
            sf = f0;
        }
    }
    __syncthreads();
    const int f32in = sf;
    const unsigned short* w1g = (const unsigned short*)W1v;
    const float* w1f = (const float*)W1v;
    for (int i = 0; i < 64; ++i) {
        int id = i * 256 + t;                 // n*128+k
        int n = id >> 7, k = id & 127;
        W1T[id] = f32in ? f2bf_bits(w1f[k * 128 + n]) : w1g[k * 128 + n];
    }
    const unsigned short* w2g = (const unsigned short*)W2v;
    const float* w2f = (const float*)W2v;
    for (int i = 0; i < 16; ++i) {
        int id = i * 256 + t;                 // n*128+k  (n<32)
        int n = id >> 7, k = id & 127;
        W2T[id] = f32in ? f2bf_bits(w2f[k * 32 + n]) : w2g[k * 32 + n];
    }
}

// ---------------- edge decode helpers ----------------------------------------
template <typename IT>
__device__ __forceinline__ void get_sd(const IT* __restrict__ ei, int idx, int& s, int& d) {
    if (idx < EE) { s = (int)ei[idx]; d = (int)ei[EE + idx]; }
    else          { s = d = idx - EE; }
}
template <typename IT>
__device__ __forceinline__ int dst_of(const IT* __restrict__ ei, int idx) {
    return idx < EE ? (int)ei[EE + idx] : idx - EE;
}

// ---------------- Layer 1 linear via MFMA: h1(bf16) = x @ W1, + logits --------
#define MROWS 64
#define LDK 136   // padded LDS row stride (elements) -> 272 B, 16B-aligned frags

__global__ __launch_bounds__(256) void k_lin1_mfma(
    const void* xv, const unsigned short* __restrict__ W1T,
    const void* as1v, const void* ad1v,
    const int* __restrict__ flags, unsigned* __restrict__ h1,
    float* __restrict__ als, float* __restrict__ ald)
{
    __shared__ __align__(16) char smem[(MROWS + 128) * LDK * 2];  // 52,224 B
    unsigned short* xs  = (unsigned short*)smem;       // [MROWS][LDK] bf16 bits
    unsigned short* w1t = xs + MROWS * LDK;            // [128][LDK]   (n-major)
    float* hs = (float*)smem;                          // phase2 alias: [MROWS][132]
    __shared__ float sa[F1], sd[F1];

    const int t = threadIdx.x;
    const int row0 = blockIdx.x * MROWS;
    const int f32in = flags[0];

    if (t < F1) {
        sa[t] = f32in ? ((const float*)as1v)[t] : cvt(((const bf16*)as1v)[t]);
        sd[t] = f32in ? ((const float*)ad1v)[t] : cvt(((const bf16*)ad1v)[t]);
    }
    if (!f32in) {
        const uint4* xg = (const uint4*)xv;            // 16 B = 8 bf16
        for (int i = 0; i < 4; ++i) {
            int id = i * 256 + t;                      // 0..1023
            int m = id >> 4, seg = id & 15;
            int gr = row0 + m;
            uint4 val = (gr < NN) ? xg[(size_t)gr * 16 + seg] : make_uint4(0, 0, 0, 0);
            *(uint4*)&xs[m * LDK + seg * 8] = val;
        }
    } else {
        const float* xf = (const float*)xv;
        for (int i = 0; i < 32; ++i) {
            int id = i * 256 + t;
            int m = id >> 7, c = id & 127;
            int gr = row0 + m;
            xs[m * LDK + c] = (gr < NN) ? f2bf_bits(xf[(size_t)gr * 128 + c]) : 0;
        }
    }
    {
        const uint4* wg = (const uint4*)W1T;           // [128][16] uint4, n-major
        for (int i = 0; i < 8; ++i) {
            int id = i * 256 + t;                      // 0..2047 = n*16+seg
            int n = id >> 4, seg = id & 15;
            *(uint4*)&w1t[n * LDK + seg * 8] = wg[id];
        }
    }
    __syncthreads();

    const int wave = t >> 6, lane = t & 63, quad = lane >> 4, l16 = lane & 15;
    f32x4 acc[8];
#pragma unroll
    for (int ni = 0; ni < 8; ++ni) acc[ni] = (f32x4){0.f, 0.f, 0.f, 0.f};

    const int arow = wave * 16 + l16;
#pragma unroll
    for (int kc = 0; kc < 4; ++kc) {
        int ko = kc * 32 + quad * 8;
        bf16x8 av = *(const bf16x8*)&xs[arow * LDK + ko];
#pragma unroll
        for (int ni = 0; ni < 8; ++ni) {
            bf16x8 bv = *(const bf16x8*)&w1t[(ni * 16 + l16) * LDK + ko];
            acc[ni] = __builtin_amdgcn_mfma_f32_16x16x32_bf16(av, bv, acc[ni], 0, 0, 0);
        }
    }
    __syncthreads();   // staging LDS dead; reuse as hs

#pragma unroll
    for (int ni = 0; ni < 8; ++ni)
#pragma unroll
        for (int r = 0; r < 4; ++r) {
            int m = wave * 16 + quad * 4 + r;          // C/D: row=quad*4+reg, col=l16
            hs[m * 132 + ni * 16 + l16] = acc[ni][r];
        }
    __syncthreads();

    for (int i = 0; i < 16; ++i) {
        int id = i * 256 + t;                          // 0..4095 word index
        int m = id >> 6, wd = id & 63;
        int gr = row0 + m;
        if (gr < NN) {
            unsigned pw = (unsigned)f2bf_bits(hs[m * 132 + 2 * wd]) |
                          ((unsigned)f2bf_bits(hs[m * 132 + 2 * wd + 1]) << 16);
            h1[(size_t)gr * 64 + wd] = pw;
        }
    }
    {
        int m = t >> 2, h = t & 3;                     // 64 nodes x 4 heads
        int gr = row0 + m;
        if (gr < NN) {
            float ps = 0.f, pd = 0.f;
#pragma unroll
            for (int j = 0; j < 32; ++j) {
                float v = hs[m * 132 + h * 32 + j];
                ps += v * sa[h * 32 + j];
                pd += v * sd[h * 32 + j];
            }
            als[gr * 4 + h] = ps;
            ald[gr * 4 + h] = pd;
        }
    }
}

// ---------------- CSR build: histogram(+rank) + 2-kernel scan -----------------
#define SCAN_B 196   // ceil(NN/256)

__global__ void k_hist(const void* ei, const int* __restrict__ flags,
                       int* __restrict__ counts, int* __restrict__ rank) {
    int idx = blockIdx.x * blockDim.x + threadIdx.x;
    if (idx >= EN) return;
    int d = flags[1] ? dst_of<long long>((const long long*)ei, idx)
                     : dst_of<int>((const int*)ei, idx);
    rank[idx] = atomicAdd(&counts[d], 1);
}

__global__ void k_scanA(const int* __restrict__ counts, int* __restrict__ bsum) {
    __shared__ int sh[256];
    int i = blockIdx.x * 256 + threadIdx.x;
    sh[threadIdx.x] = (i < NN) ? counts[i] : 0;
    __syncthreads();
    for (int off = 128; off > 0; off >>= 1) {
        if (threadIdx.x < off) sh[threadIdx.x] += sh[threadIdx.x + off];
        __syncthreads();
    }
    if (threadIdx.x == 0) bsum[blockIdx.x] = sh[0];
}

// per-block: tree-reduce bsum[0..b) for the base, then local scan
__global__ void k_scanC(const int* __restrict__ counts, const int* __restrict__ bsum,
                        int* __restrict__ offsets) {
    __shared__ int red[256];
    __shared__ int sh[256];
    const int t = threadIdx.x, b = blockIdx.x;
    red[t] = (t < b) ? bsum[t] : 0;        // b <= 195 < 256
    __syncthreads();
    for (int off = 128; off > 0; off >>= 1) {
        if (t < off) red[t] += red[t + off];
        __syncthreads();
    }
    const int base = red[0];
    int i = b * 256 + t;
    int v = (i < NN) ? counts[i] : 0;
    sh[t] = v;
    __syncthreads();
    for (int off = 1; off < 256; off <<= 1) {
        int u = (t >= off) ? sh[t - off] : 0;
        __syncthreads();
        sh[t] += u;
        __syncthreads();
    }
    if (i < NN) {
        offsets[i] = base + sh[t] - v;
    } else if (i == NN) {
        offsets[NN] = EN;                    // total is static
    }
}

// ---- scatter (no atomic): one 16B record/edge = {src, exp01, exp23, 0} -------
__global__ void k_scatter(const void* ei, const int* __restrict__ flags,
                          const int* __restrict__ offsets, const int* __restrict__ rank,
                          const float4* __restrict__ als, const float4* __restrict__ ald,
                          uint4* __restrict__ rec) {
    int idx = blockIdx.x * blockDim.x + threadIdx.x;
    if (idx >= EN) return;
    int s, d;
    if (flags[1]) get_sd<long long>((const long long*)ei, idx, s, d);
    else          get_sd<int>((const int*)ei, idx, s, d);
    int slot = offsets[d] + rank[idx];
    float4 a = als[s], b = ald[d];
    float e0 = a.x + b.x, e1 = a.y + b.y, e2 = a.z + b.z, e3 = a.w + b.w;
    e0 = e0 > 0.f ? e0 : NEG * e0;
    e1 = e1 > 0.f ? e1 : NEG * e1;
    e2 = e2 > 0.f ? e2 : NEG * e2;
    e3 = e3 > 0.f ? e3 : NEG * e3;
    unsigned w0 = (unsigned)f2h_bits(__expf(e0)) | ((unsigned)f2h_bits(__expf(e1)) << 16);
    unsigned w1 = (unsigned)f2h_bits(__expf(e2)) | ((unsigned)f2h_bits(__expf(e3)) << 16);
    rec[slot] = make_uint4((unsigned)s, w0, w1, 0u);
}

// ---- Layer 1 aggregate: 1 wave/node, half-wave/edge, unroll x4, rec stream,
//      fused bias+ELU, bf16 output (hm). NO barrier (round-10 lesson). --------
__global__ __launch_bounds__(256) void k_agg1(
    const int* __restrict__ offsets, const uint4* __restrict__ rec,
    const bf16* __restrict__ h1, const void* b1v, const int* __restrict__ flags,
    uint2* __restrict__ hm)
{
    const int lane = threadIdx.x & 63;
    const int d = blockIdx.x * 4 + (threadIdx.x >> 6);
    const int q = lane >> 5;           // half: even/odd edges
    const int u = lane & 31;           // uint2 index in row -> channels 4u..4u+3
    const int h = u >> 3;              // head of these channels
    const int start = offsets[d], end = offsets[d + 1];
    const uint2* rows = (const uint2*)h1;   // 32 uint2 per 256 B row

    float A0[4] = {0,0,0,0}, A1[4] = {0,0,0,0}, A2[4] = {0,0,0,0}, A3[4] = {0,0,0,0};
    float D[4] = {0,0,0,0};
    int e = start + q;
    for (; e + 6 < end; e += 8) {
        uint4 r0 = rec[e],     r1 = rec[e + 2];
        uint4 r2 = rec[e + 4], r3 = rec[e + 6];
        float x0 = rec_exp(r0, h), x1 = rec_exp(r1, h);
        float x2 = rec_exp(r2, h), x3 = rec_exp(r3, h);
        uint2 u0 = rows[r0.x * 32 + u], u1 = rows[r1.x * 32 + u];
        uint2 u2 = rows[r2.x * 32 + u], u3 = rows[r3.x * 32 + u];
        A0[0] += x0 * bflo(u0.x); A0[1] += x0 * bfhi(u0.x);
        A0[2] += x0 * bflo(u0.y); A0[3] += x0 * bfhi(u0.y); D[0] += x0;
        A1[0] += x1 * bflo(u1.x); A1[1] += x1 * bfhi(u1.x);
        A1[2] += x1 * bflo(u1.y); A1[3] += x1 * bfhi(u1.y); D[1] += x1;
        A2[0] += x2 * bflo(u2.x); A2[1] += x2 * bfhi(u2.x);
        A2[2] += x2 * bflo(u2.y); A2[3] += x2 * bfhi(u2.y); D[2] += x2;
        A3[0] += x3 * bflo(u3.x); A3[1] += x3 * bfhi(u3.x);
        A3[2] += x3 * bflo(u3.y); A3[3] += x3 * bfhi(u3.y); D[3] += x3;
    }
    for (; e < end; e += 2) {
        uint4 r0 = rec[e];
        float x0 = rec_exp(r0, h);
        uint2 u0 = rows[r0.x * 32 + u];
        A0[0] += x0 * bflo(u0.x); A0[1] += x0 * bfhi(u0.x);
        A0[2] += x0 * bflo(u0.y); A0[3] += x0 * bfhi(u0.y); D[0] += x0;
    }
    float a0 = A0[0] + A1[0] + A2[0] + A3[0];
    float a1 = A0[1] + A1[1] + A2[1] + A3[1];
    float a2 = A0[2] + A1[2] + A2[2] + A3[2];
    float a3 = A0[3] + A1[3] + A2[3] + A3[3];
    float dsum = D[0] + D[1] + D[2] + D[3];
    a0 += __shfl_xor(a0, 32); a1 += __shfl_xor(a1, 32);
    a2 += __shfl_xor(a2, 32); a3 += __shfl_xor(a3, 32);
    dsum += __shfl_xor(dsum, 32);
    if (q == 0) {
        float inv = 1.f / (dsum + 1e-16f);
        float bb0, bb1, bb2, bb3;
        if (flags[0]) {
            float4 bb = ((const float4*)b1v)[u];
            bb0 = bb.x; bb1 = bb.y; bb2 = bb.z; bb3 = bb.w;
        } else {
            uint2 ub = ((const uint2*)b1v)[u];
            bb0 = bflo(ub.x); bb1 = bfhi(ub.x); bb2 = bflo(ub.y); bb3 = bfhi(ub.y);
        }
        float v0 = a0 * inv + bb0, v1 = a1 * inv + bb1;
        float v2 = a2 * inv + bb2, v3 = a3 * inv + bb3;
        v0 = v0 > 0.f ? v0 : (__expf(v0) - 1.f);   // ELU
        v1 = v1 > 0.f ? v1 : (__expf(v1) - 1.f);
        v2 = v2 > 0.f ? v2 : (__expf(v2) - 1.f);
        v3 = v3 > 0.f ? v3 : (__expf(v3) - 1.f);
        unsigned w0 = (unsigned)f2bf_bits(v0) | ((unsigned)f2bf_bits(v1) << 16);
        unsigned w1 = (unsigned)f2bf_bits(v2) | ((unsigned)f2bf_bits(v3) << 16);
        hm[(size_t)d * 32 + u] = make_uint2(w0, w1);
    }
}

// ---------------- Mid via MFMA: h2(f16) = hm @ W2, + layer-2 logits -----------
__global__ __launch_bounds__(256) void k_mid_mfma(
    const bf16* __restrict__ hm, const unsigned short* __restrict__ W2T,
    const void* as2v, const void* ad2v,
    const int* __restrict__ flags, unsigned short* __restrict__ h2,
    float* __restrict__ als2, float* __restrict__ ald2)
{
    __shared__ __align__(16) unsigned short hs[MROWS * LDK];   // 17,408 B
    __shared__ __align__(16) unsigned short w2t[32 * LDK];     // 8,704 B
    __shared__ float sa2[HID], sd2[HID];

    const int t = threadIdx.x;
    const int row0 = blockIdx.x * MROWS;
    const int f32in = flags[0];

    if (t < HID) {
        sa2[t] = f32in ? ((const float*)as2v)[t] : cvt(((const bf16*)as2v)[t]);
        sd2[t] = f32in ? ((const float*)ad2v)[t] : cvt(((const bf16*)ad2v)[t]);
    }
    {
        const uint4* hg = (const uint4*)hm;
        for (int i = 0; i < 4; ++i) {
            int id = i * 256 + t;                      // 0..1023
            int m = id >> 4, seg = id & 15;
            int gr = row0 + m;
            uint4 val = (gr < NN) ? hg[(size_t)gr * 16 + seg] : make_uint4(0, 0, 0, 0);
            *(uint4*)&hs[m * LDK + seg * 8] = val;
        }
        const uint4* wg = (const uint4*)W2T;           // [32][16] uint4, n-major
        for (int i = 0; i < 2; ++i) {
            int id = i * 256 + t;                      // 0..511 = n*16+seg
            int n = id >> 4, seg = id & 15;
            *(uint4*)&w2t[n * LDK + seg * 8] = wg[id];
        }
    }
    __syncthreads();

    const int wave = t >> 6, lane = t & 63, quad = lane >> 4, l16 = lane & 15;
    f32x4 acc[2];
    acc[0] = (f32x4){0.f, 0.f, 0.f, 0.f};
    acc[1] = (f32x4){0.f, 0.f, 0.f, 0.f};
    const int arow = wave * 16 + l16;
#pragma unroll
    for (int kc = 0; kc < 4; ++kc) {
        int ko = kc * 32 + quad * 8;
        bf16x8 av = *(const bf16x8*)&hs[arow * LDK + ko];
#pragma unroll
        for (int ni = 0; ni < 2; ++ni) {
            bf16x8 bv = *(const bf16x8*)&w2t[(ni * 16 + l16) * LDK + ko];
            acc[ni] = __builtin_amdgcn_mfma_f32_16x16x32_bf16(av, bv, acc[ni], 0, 0, 0);
        }
    }

    // h2 (f16) stores straight from registers (C/D: row=quad*4+r, col=ni*16+l16)
#pragma unroll
    for (int ni = 0; ni < 2; ++ni)
#pragma unroll
        for (int r = 0; r < 4; ++r) {
            int gr = row0 + wave * 16 + quad * 4 + r;
            if (gr < NN) h2[(size_t)gr * 32 + ni * 16 + l16] = f2h_bits(acc[ni][r]);
        }

    // logits: per-row dot with a_src2/a_dst2, 16-lane butterfly reduction
    float ps[4], pd[4];
#pragma unroll
    for (int r = 0; r < 4; ++r) {
        ps[r] = acc[0][r] * sa2[l16] + acc[1][r] * sa2[16 + l16];
        pd[r] = acc[0][r] * sd2[l16] + acc[1][r] * sd2[16 + l16];
    }
#pragma unroll
    for (int mask = 1; mask < 16; mask <<= 1)
#pragma unroll
        for (int r = 0; r < 4; ++r) {
            ps[r] += __shfl_xor(ps[r], mask);
            pd[r] += __shfl_xor(pd[r], mask);
        }
    if (l16 == 0) {
#pragma unroll
        for (int r = 0; r < 4; ++r) {
            int gr = row0 + wave * 16 + quad * 4 + r;
            if (gr < NN) { als2[gr] = ps[r]; ald2[gr] = pd[r]; }
        }
    }
}

// ---- Layer 2 aggregate: 1 wave/node, 16 lanes/edge (q=0..3), unroll x2 -------
__global__ __launch_bounds__(256) void k_agg2(
    const int* __restrict__ offsets, const uint4* __restrict__ rec,
    const float* __restrict__ als2, const float* __restrict__ ald2,
    const unsigned* __restrict__ h2,   // f16 pairs, 16 per row
    const void* b2v, const int* __restrict__ flags, void* out)
{
    const int lane = threadIdx.x & 63;
    const int node = blockIdx.x * 4 + (threadIdx.x >> 6);
    const int q = lane >> 4;           // 0..3: edge sub-stream
    const int u = lane & 15;           // uint index: channels 2u, 2u+1
    const int start = offsets[node], end = offsets[node + 1];
    const float adv = ald2[node];

    float A0 = 0.f, A1 = 0.f, B0 = 0.f, B1 = 0.f, D0 = 0.f, D1 = 0.f;
    int e = start + q;
    for (; e + 4 < end; e += 8) {
        int s0 = (int)rec[e].x, s1 = (int)rec[e + 4].x;
        float e0 = als2[s0] + adv, e1 = als2[s1] + adv;
        e0 = e0 > 0.f ? e0 : NEG * e0;
        e1 = e1 > 0.f ? e1 : NEG * e1;
        float x0 = __expf(e0), x1 = __expf(e1);
        unsigned w0 = h2[s0 * 16 + u];
        unsigned w1 = h2[s1 * 16 + u];
        A0 += x0 * h2f((unsigned short)(w0 & 0xFFFFu));
        A1 += x0 * h2f((unsigned short)(w0 >> 16));  D0 += x0;
        B0 += x1 * h2f((unsigned short)(w1 & 0xFFFFu));
        B1 += x1 * h2f((unsigned short)(w1 >> 16));  D1 += x1;
    }
    for (; e < end; e += 4) {
        int s0 = (int)rec[e].x;
        float e0 = als2[s0] + adv;
        e0 = e0 > 0.f ? e0 : NEG * e0;
        float x0 = __expf(e0);
        unsigned w0 = h2[s0 * 16 + u];
        A0 += x0 * h2f((unsigned short)(w0 & 0xFFFFu));
        A1 += x0 * h2f((unsigned short)(w0 >> 16));  D0 += x0;
    }
    float a0 = A0 + B0, a1 = A1 + B1, dsum = D0 + D1;
    a0 += __shfl_xor(a0, 16); a1 += __shfl_xor(a1, 16); dsum += __shfl_xor(dsum, 16);
    a0 += __shfl_xor(a0, 32); a1 += __shfl_xor(a1, 32); dsum += __shfl_xor(dsum, 32);
    if (q == 0) {
        float inv = 1.f / (dsum + 1e-16f);
        float r0 = a0 * inv, r1 = a1 * inv;
        if (flags[0]) {
            float2 bb = ((const float2*)b2v)[u];
            ((float2*)out)[(size_t)node * 16 + u] = make_float2(r0 + bb.x, r1 + bb.y);
        } else {
            unsigned ub = ((const unsigned*)b2v)[u];
            r0 += bflo(ub); r1 += bfhi(ub);
            ((unsigned*)out)[(size_t)node * 16 + u] =
                (unsigned)f2bf_bits(r0) | ((unsigned)f2bf_bits(r1) << 16);
        }
    }
}

extern "C" void kernel_launch(void* const* d_in, const int* in_sizes, int n_in,
                              void* d_out, int out_size, void* d_ws, size_t ws_size,
                              hipStream_t stream) {
    const void* x    = d_in[0];
    const void* ei   = d_in[1];
    const void* W1   = d_in[2];
    const void* a_s1 = d_in[3];
    const void* a_d1 = d_in[4];
    const void* b1   = d_in[5];
    const void* W2   = d_in[6];
    const void* a_s2 = d_in[7];
    const void* a_d2 = d_in[8];
    const void* b2v  = d_in[9];

    // ---- workspace layout (~41.7 MB) ----
    int*   flags  = (int*)d_ws;
    char*  pc     = (char*)d_ws + 256;
    uint2* hm     = (uint2*)pc;            pc += (size_t)NN * 32 * 8;   // bf16 [NN][128], 12.8 MB
    int*   rank   = (int*)hm;              // alias: rank ∈ [hist,scatter], hm ∈ [agg1,mid]
    bf16*  h1     = (bf16*)pc;             pc += (size_t)NN * F1 * 2;   // 12.8 MB
    unsigned short* h2 = (unsigned short*)h1;  // f16 [NN][32] alias (h1 dead after agg1)
    uint4* rec    = (uint4*)pc;            pc += (size_t)EN * 16;      // 13.6 MB
    float* al_s1  = (float*)pc;            pc += (size_t)NN * HEADS * 4;
    float* al_d1  = (float*)pc;            pc += (size_t)NN * HEADS * 4;
    float* al_s2  = (float*)pc;            pc += (size_t)NN * 4;
    float* al_d2  = (float*)pc;            pc += (size_t)NN * 4;
    int*   offs   = (int*)pc;              pc += (size_t)(NN + 4) * 4;
    int*   counts = (int*)pc;              pc += (size_t)NN * 4;
    unsigned short* W1T = (unsigned short*)pc; pc += (size_t)128 * 128 * 2;
    unsigned short* W2T = (unsigned short*)pc; pc += (size_t)32 * 128 * 2;
    int*   bsum   = (int*)pc;              pc += SCAN_B * 4;

    hipMemsetAsync(counts, 0, (size_t)NN * sizeof(int), stream);

    k_prep<<<1, 256, 0, stream>>>(x, ei, W1, W2, flags, W1T, W2T);
    k_hist<<<(EN + 255) / 256, 256, 0, stream>>>(ei, flags, counts, rank);
    k_scanA<<<SCAN_B, 256, 0, stream>>>(counts, bsum);
    k_scanC<<<SCAN_B, 256, 0, stream>>>(counts, bsum, offs);
    k_lin1_mfma<<<(NN + MROWS - 1) / MROWS, 256, 0, stream>>>(x, W1T, a_s1, a_d1,
                                                              flags, (unsigned*)h1,
                                                              al_s1, al_d1);
    k_scatter<<<(EN + 255) / 256, 256, 0, stream>>>(ei, flags, offs, rank,
                                                    (const float4*)al_s1,
                                                    (const float4*)al_d1, rec);
    k_agg1<<<NN / 4, 256, 0, stream>>>(offs, rec, h1, b1, flags, hm);
    k_mid_mfma<<<(NN + MROWS - 1) / MROWS, 256, 0, stream>>>((const bf16*)hm, W2T, a_s2,
                                                             a_d2, flags, h2, al_s2, al_d2);
    k_agg2<<<NN / 4, 256, 0, stream>>>(offs, rec, al_s2, al_d2, (const unsigned*)h2,
                                       b2v, flags, d_out);
}